// Round 11
// baseline (3074.712 us; speedup 1.0000x reference)
//
#include <hip/hip_runtime.h>
#include <hip/hip_bf16.h>
#include <math.h>

// Problem constants
#define Sn 3
#define Hn 64
#define Dn 12
#define Bn 512
#define Ln 512
#define BC 4            // batch elems per workgroup (one per wave for E-phase)
#define IN0 76          // D + H
#define NIN 22
#define CT 32           // timesteps per chunk
#define NCHUNK (Ln / CT)
// mega grid layout: [0,384) pass2 | [384,768) pass1 | [768,1026) g1r | [1026,1538) combine
#define P2OFF 0
#define P1OFF 384
#define GROFF 768
#define CBOFF 1026
#define MEGABLK 1538

// double-buffered intermediate sizes (elements)
#define NINP ((size_t)3 * Bn * CT * 64)     // f16
#define NG1R ((size_t)3 * Bn * CT * 320)    // f16
#define NMERG ((size_t)3 * Bn * CT * 64)    // bf16 (ushort)

using bf16 = __hip_bfloat16;
typedef _Float16 h2 __attribute__((ext_vector_type(2)));
typedef _Float16 h4 __attribute__((ext_vector_type(4)));
typedef _Float16 h8t __attribute__((ext_vector_type(8)));
typedef int i2v __attribute__((ext_vector_type(2)));

__device__ __forceinline__ float u2f(unsigned short x) {
    return __uint_as_float(((unsigned int)x) << 16);
}
__device__ __forceinline__ unsigned short f2u(float f) {
    bf16 h = __float2bfloat16(f);
    unsigned short u;
    __builtin_memcpy(&u, &h, 2);
    return u;
}

// ---- fast transcendentals (exact algebraic forms on v_exp_f32 / v_rcp_f32) ----
__device__ __forceinline__ float ex2(float x) {
#if __has_builtin(__builtin_amdgcn_exp2f)
    return __builtin_amdgcn_exp2f(x);
#else
    return exp2f(x);
#endif
}
__device__ __forceinline__ float frcp(float x) {
#if __has_builtin(__builtin_amdgcn_rcpf)
    return __builtin_amdgcn_rcpf(x);
#else
    return 1.0f / x;
#endif
}
__device__ __forceinline__ float sigm(float x) {
    return frcp(1.0f + ex2(-1.44269504f * x));
}
__device__ __forceinline__ float tanhfast(float x) {
    // tanh(x) = 1 - 2/(exp(2x)+1); exp(2x) = exp2(2.885390x). Saturates correctly.
    return 1.0f - 2.0f * frcp(1.0f + ex2(2.88539008f * x));
}
__device__ __forceinline__ float gelu_ex(float x) { return 0.5f * x * (1.0f + erff(x * 0.70710678118654752f)); }

// ---- f16 dot2 helpers (v_dot2_f32_f16: 2 MACs/instr, fp32 accumulate) ----
__device__ __forceinline__ float fdot2f(h2 a, h2 b, float c) {
#if __has_builtin(__builtin_amdgcn_fdot2)
    return __builtin_amdgcn_fdot2(a, b, c, false);
#else
    return fmaf((float)a.x, (float)b.x, fmaf((float)a.y, (float)b.y, c));
#endif
}
__device__ __forceinline__ h2 cvt2(float x, float y) {
    h2 r; r.x = (_Float16)x; r.y = (_Float16)y; return r;
}
__device__ __forceinline__ h2 mk2(_Float16 a, _Float16 b) {
    h2 r; r.x = a; r.y = b; return r;
}
__device__ __forceinline__ void unpack8(h8t v, h2* out) {
    out[0] = __builtin_shufflevector(v, v, 0, 1);
    out[1] = __builtin_shufflevector(v, v, 2, 3);
    out[2] = __builtin_shufflevector(v, v, 4, 5);
    out[3] = __builtin_shufflevector(v, v, 6, 7);
}

// ---- cross-lane reductions (pure VALU/DPP where gfx950 allows) ----
template <int CTRL>
__device__ __forceinline__ float qp(float v) {
    return __int_as_float(__builtin_amdgcn_update_dpp(0, __float_as_int(v), CTRL, 0xF, 0xF, true));
}
__device__ __forceinline__ float qsum(float v) {
    v += qp<0xB1>(v);   // xor1 (quad perm)
    v += qp<0x4E>(v);   // xor2
    return v;
}
// 8-lane (octet) sum: after qsum v is quad-uniform, so row_half_mirror
// (mirror within 8) fetches the other quad's sum -> no LDS op.
__device__ __forceinline__ float osum(float v) {
    v = qsum(v);
    v += qp<0x141>(v);  // half_mirror: cross-quad within octet
    return v;
}
__device__ __forceinline__ float xadd16(float v) {
#if __has_builtin(__builtin_amdgcn_permlane16_swap)
    i2v r = __builtin_amdgcn_permlane16_swap(__float_as_int(v), __float_as_int(v), false, false);
    return __int_as_float(r.x) + __int_as_float(r.y);
#else
    return v + __int_as_float(__builtin_amdgcn_ds_swizzle(__float_as_int(v), 0x401F));
#endif
}
__device__ __forceinline__ float xadd32(float v) {
#if __has_builtin(__builtin_amdgcn_permlane32_swap)
    i2v r = __builtin_amdgcn_permlane32_swap(__float_as_int(v), __float_as_int(v), false, false);
    return __int_as_float(r.x) + __int_as_float(r.y);
#else
    return v + __shfl_xor(v, 32, 64);
#endif
}
// full-wave sum: 4 DPP + 2 permlane swaps — zero LDS-pipe ops
__device__ __forceinline__ float redsum64(float v) {
    v += qp<0xB1>(v);
    v += qp<0x4E>(v);
    v += qp<0x141>(v);
    v += qp<0x140>(v);
    v = xadd16(v);
    v = xadd32(v);
    return v;
}

// ---------------------------------------------------------------------------
// canonicalize all inputs to fp32 in ws.  Each block recomputes the dtype
// decision locally from the (L2-resident) first 2048 halfwords of x.
// ---------------------------------------------------------------------------
struct ConvArgs {
    const void* src[NIN];
    unsigned dstOff[NIN];
    unsigned n[NIN];
    unsigned blockStart[NIN + 1];
};

__global__ __launch_bounds__(256) void convert_kernel(ConvArgs a, float* __restrict__ dst) {
    __shared__ int sh[4];
    int tid = threadIdx.x;
    const unsigned short* xr = (const unsigned short*)a.src[0];
    int cnt = 0;
    for (int ii = tid; ii < 2048; ii += 256) {
        unsigned e = (xr[ii] >> 7) & 0xFF;
        if (e >= 110 && e <= 133) cnt++;
    }
    for (int o = 32; o > 0; o >>= 1) cnt += __shfl_xor(cnt, o, 64);
    if ((tid & 63) == 0) sh[tid >> 6] = cnt;
    __syncthreads();
    bool isf32 = (sh[0] + sh[1] + sh[2] + sh[3]) < 1640;

    int bid = blockIdx.x;
    int i = 0;
    while (i < NIN - 1 && bid >= (int)a.blockStart[i + 1]) i++;
    unsigned lb = (unsigned)bid - a.blockStart[i];
    unsigned base = lb * 2048 + tid;
    unsigned n = a.n[i];
    float* d = dst + a.dstOff[i];
    const float* sf = (const float*)a.src[i];
    const unsigned short* su = (const unsigned short*)a.src[i];
#pragma unroll
    for (int e = 0; e < 8; e++) {
        unsigned idx = base + e * 256;
        if (idx < n) d[idx] = isf32 ? sf[idx] : u2f(su[idx]);
    }
}

// ---------------------------------------------------------------------------
// Setup (one launch, 10 blocks): fuse | perm | dtype flag
// ---------------------------------------------------------------------------
__global__ __launch_bounds__(256) void setup_kernel(
    const unsigned short* __restrict__ xr, int* __restrict__ flag,
    const float* __restrict__ mi_w, const float* __restrict__ mi_b,
    const float* __restrict__ mo_w, const float* __restrict__ mo_b,
    const float* __restrict__ w1, const float* __restrict__ b1,
    float* __restrict__ M1out, float* __restrict__ bias1out,
    const float* __restrict__ gw1, const float* __restrict__ gb1,
    const float* __restrict__ rw1,
    h2* __restrict__ gw1p16, float* __restrict__ gb1p,
    h2* __restrict__ rw1p16) {
    int bid = blockIdx.x;
    int tid = threadIdx.x;
    if (bid < 6) {
        int sl = bid;
        __shared__ float T[64][64];
        __shared__ float bT[64];
        const float* Mv = mi_w + sl * 64 * 192;
        const float* Mo = mo_w + sl * 64 * 64;
        for (int idx = tid; idx < 64 * 64; idx += 256) {
            int k = idx >> 6, n = idx & 63;
            float acc = 0.f;
            for (int j = 0; j < 64; j++) acc += Mv[k * 192 + 128 + j] * Mo[j * 64 + n];
            T[k][n] = acc;
        }
        for (int n = tid; n < 64; n += 256) {
            float acc = mo_b[sl * 64 + n];
            for (int j = 0; j < 64; j++) acc += mi_b[sl * 192 + 128 + j] * Mo[j * 64 + n];
            bT[n] = acc;
        }
        __syncthreads();
        const float* W1 = w1 + sl * 64 * 128;
        for (int idx = tid; idx < 64 * 128; idx += 256) {
            int k = idx >> 7, m = idx & 127;
            float acc = 0.f;
            for (int n = 0; n < 64; n++) acc += T[k][n] * W1[n * 128 + m];
            M1out[sl * 64 * 128 + idx] = acc;
        }
        for (int m = tid; m < 128; m += 256) {
            float acc = b1[sl * 128 + m];
            for (int n = 0; n < 64; n++) acc += bT[n] * W1[n * 128 + m];
            bias1out[sl * 128 + m] = acc;
        }
    } else if (bid < 9) {
        int s = bid - 6;
        const float* G = gw1 + (size_t)s * 128 * 256;
        for (int idx = tid; idx < 32 * 256; idx += 256) {
            int k2 = idx >> 8, p = idx & 255;
            int c = (p & 3) * 64 + ((p >> 6) << 4) + ((p >> 2) & 15);
            gw1p16[((size_t)s * 32 + k2) * 256 + p] =
                cvt2(G[(2 * k2) * 256 + c], G[(2 * k2 + 1) * 256 + c]);
        }
        for (int p = tid; p < 256; p += 256) {
            int c = (p & 3) * 64 + ((p >> 6) << 4) + ((p >> 2) & 15);
            gb1p[s * 256 + p] = gb1[s * 256 + c];
        }
        const float* R = rw1 + (size_t)s * 64 * 64;
        for (int idx = tid; idx < 32 * 64; idx += 256) {
            int k2 = idx >> 6, c = idx & 63;
            rw1p16[((size_t)s * 32 + k2) * 64 + c] =
                cvt2(R[(2 * k2) * 64 + c], R[(2 * k2 + 1) * 64 + c]);
        }
    } else {
        __shared__ int sh[4];
        int cnt = 0;
        for (int ii = tid; ii < 2048; ii += 256) {
            unsigned e = (xr[ii] >> 7) & 0xFF;
            if (e >= 110 && e <= 133) cnt++;
        }
        for (int o = 32; o > 0; o >>= 1) cnt += __shfl_xor(cnt, o, 64);
        if ((tid & 63) == 0) sh[tid >> 6] = cnt;
        __syncthreads();
        if (tid == 0) {
            int tot = sh[0] + sh[1] + sh[2] + sh[3];
            *flag = (tot < 1640) ? 1 : 0;
        }
    }
}

// ---------------------------------------------------------------------------
// Pass 1 body: layer 0 over a T-chunk. bid in [0,384).
// Per-timestep OUTPUTS go to LDS scratch (no global stores on the barrier-
// drained critical path); dumped to inp_w in one coalesced burst at the end.
// Per-timestep x loads hoisted to the TOP of the timestep (phase A covers
// their latency before the first barrier drain).
// ---------------------------------------------------------------------------
__device__ __forceinline__ void pass1_body(
    int bid,
    const float* __restrict__ x, const float* __restrict__ gw0,
    const float* __restrict__ gb0,
    const float* __restrict__ M1g, const float* __restrict__ bias1g,
    const float* __restrict__ w2g, const float* __restrict__ b2g,
    const float* __restrict__ lag, const float* __restrict__ lab,
    const float* __restrict__ log_, const float* __restrict__ lob,
    const float* __restrict__ rw0, const float* __restrict__ rb0,
    float* __restrict__ gstate, _Float16* __restrict__ inp_w,
    _Float16* __restrict__ s_buf, int t0) {
    const int tid = threadIdx.x;
    const int sIdx = bid >> 7;
    const int gbase = (bid & 127) * BC;
    const int W = tid >> 6, lane = tid & 63;
    const int q = lane >> 2, ks = lane & 3;
    const int oct = lane >> 3, ks8 = lane & 7;
    const int j = W * 16 + q;
    const int cM = W * 32 + q * 2;
    const int uD = W * 16 + oct * 2;

    const int Li = (sIdx == 0) ? 170 : (sIdx == 1 ? 512 : 256);
    const int st = (sIdx == 0) ? 342 : (sIdx == 1 ? 0 : 256);
    const float sc = (float)Li / 512.0f;

    __shared__ float s_x[2][BC][12];
    __shared__ __align__(16) _Float16 s_h16[BC][72];    // 144B rows: bank-shift 4
    __shared__ __align__(16) _Float16 s_ht16[BC][72];
    __shared__ __align__(16) _Float16 s_z16[BC][136];   // 272B rows
    __shared__ float s_t2[BC][64];
    __shared__ float s_rw0[768];

    __builtin_amdgcn_s_setprio(1);   // recurrent chain = critical path

    const float* gw0s = gw0 + sIdx * IN0 * 256;
    float wx[12];
    h2 wg16[4][8], wm16[2][8], ww16[2][8];
#pragma unroll
    for (int g = 0; g < 4; g++)
#pragma unroll
        for (int d = 0; d < 3; d++) wx[g * 3 + d] = gw0s[(ks * 3 + d) * 256 + j + 64 * g];
#pragma unroll
    for (int g = 0; g < 4; g++)
#pragma unroll
        for (int kk = 0; kk < 8; kk++)
            wg16[g][kk] = cvt2(gw0s[(12 + ks * 16 + 2 * kk) * 256 + j + 64 * g],
                               gw0s[(12 + ks * 16 + 2 * kk + 1) * 256 + j + 64 * g]);
    const float* M1s = M1g + (sIdx * 2 + 0) * 8192;
#pragma unroll
    for (int cc = 0; cc < 2; cc++)
#pragma unroll
        for (int kk = 0; kk < 8; kk++)
            wm16[cc][kk] = cvt2(M1s[(ks * 16 + 2 * kk) * 128 + cM + cc],
                                M1s[(ks * 16 + 2 * kk + 1) * 128 + cM + cc]);
    const float* w2s = w2g + (sIdx * 2 + 0) * 8192;
#pragma unroll
    for (int cc = 0; cc < 2; cc++)
#pragma unroll
        for (int kk = 0; kk < 8; kk++)
            ww16[cc][kk] = cvt2(w2s[(ks8 * 16 + 2 * kk) * 64 + uD + cc],
                                w2s[(ks8 * 16 + 2 * kk + 1) * 64 + uD + cc]);

    float h_gb[4];
#pragma unroll
    for (int g = 0; g < 4; g++) h_gb[g] = gb0[sIdx * 256 + j + 64 * g];
    float h_b1[2] = {bias1g[(sIdx * 2 + 0) * 128 + cM], bias1g[(sIdx * 2 + 0) * 128 + cM + 1]};
    float h_b2[2] = {b2g[(sIdx * 2 + 0) * 64 + uD], b2g[(sIdx * 2 + 0) * 64 + uD + 1]};
    int ei = (sIdx * 2 + 0) * 64 + lane;
    float eLag = lag[ei], eLab = lab[ei], eLog = log_[ei], eLob = lob[ei];
    float eRb0 = rb0[sIdx * 64 + lane];

    for (int i = tid; i < 768; i += 256) s_rw0[i] = rw0[sIdx * 768 + i];
    {
        int b = tid >> 6, jj = tid & 63;
        float hv = (t0 == 0) ? 0.f : gstate[((size_t)(sIdx * Bn + gbase + b)) * 256 + jj];
        s_h16[b][jj] = (_Float16)hv;
    }
    float cS = (t0 == 0) ? 0.f
                         : gstate[((size_t)(sIdx * Bn + gbase + ks)) * 256 + 64 + j];
    if (tid < BC * 12) {
        int b = tid / 12, d = tid % 12;
        float srcp = fmaxf((t0 + 0.5f) * sc - 0.5f, 0.f);
        int i0 = (int)floorf(srcp); if (i0 > Li - 1) i0 = Li - 1;
        int i1 = i0 + 1; if (i1 > Li - 1) i1 = Li - 1;
        float w = srcp - (float)i0;
        int gb = gbase + b;
        s_x[0][b][d] = x[(gb * Ln + st + i0) * 12 + d] * (1.0f - w) + x[(gb * Ln + st + i1) * 12 + d] * w;
    }
    __syncthreads();

    for (int tt = 0; tt < CT; tt++) {
        const int sl = tt & 1;
        // hoisted x prefetch for t+1 (loads issued BEFORE phase A so the gate
        // compute covers their latency before any barrier drain; LDS write in E)
        float px0 = 0.f, px1 = 0.f, pw = 0.f;
        if (tt + 1 < CT && lane < 12) {
            int t = t0 + tt + 1;
            float srcp = fmaxf((t + 0.5f) * sc - 0.5f, 0.f);
            int i0 = (int)floorf(srcp); if (i0 > Li - 1) i0 = Li - 1;
            int i1 = i0 + 1; if (i1 > Li - 1) i1 = Li - 1;
            pw = srcp - (float)i0;
            int gb = gbase + W;
            px0 = x[(gb * Ln + st + i0) * 12 + lane];
            px1 = x[(gb * Ln + st + i1) * 12 + lane];
        }
        // ===== A: gates0 + cell =====
        float myF = 0, myI = 0, myG = 0, myO = 0;
#pragma unroll
        for (int b = 0; b < BC; b++) {
            const h8t* hp = (const h8t*)&s_h16[b][ks * 16];
            h8t hv0 = hp[0], hv1 = hp[1];
            h2 hk[8];
            unpack8(hv0, hk); unpack8(hv1, hk + 4);
            float x0 = s_x[sl][b][ks * 3], x1 = s_x[sl][b][ks * 3 + 1], x2 = s_x[sl][b][ks * 3 + 2];
            float acc[4];
#pragma unroll
            for (int g = 0; g < 4; g++) {
                float s0 = (ks == 0) ? h_gb[g] : 0.f;
                acc[g] = fmaf(wx[g * 3], x0, fmaf(wx[g * 3 + 1], x1, fmaf(wx[g * 3 + 2], x2, s0)));
            }
#pragma unroll
            for (int kk = 0; kk < 8; kk++) {
#pragma unroll
                for (int g = 0; g < 4; g++)
                    acc[g] = fdot2f(wg16[g][kk], hk[kk], acc[g]);
            }
            float a0 = qsum(acc[0]);
            float a1 = qsum(acc[1]);
            float a2 = qsum(acc[2]);
            float a3 = qsum(acc[3]);
            if (ks == b) { myF = a0; myI = a1; myG = a2; myO = a3; }
        }
        {
            float cn = sigm(myF) * cS + sigm(myI) * tanhfast(myG);
            cS = cn;
            s_ht16[ks][j] = (_Float16)(sigm(myO) * tanhfast(cn));
        }
        __syncthreads();
        // ===== C: z = gelu(ht @ M1_0 + bias1) =====
        float z0 = 0, z1 = 0;
#pragma unroll
        for (int b = 0; b < BC; b++) {
            const h8t* hp = (const h8t*)&s_ht16[b][ks * 16];
            h8t hv0 = hp[0], hv1 = hp[1];
            h2 hk[8];
            unpack8(hv0, hk); unpack8(hv1, hk + 4);
            float acc0 = (ks == 0) ? h_b1[0] : 0.f;
            float acc1 = (ks == 0) ? h_b1[1] : 0.f;
#pragma unroll
            for (int kk = 0; kk < 8; kk++) {
                acc0 = fdot2f(wm16[0][kk], hk[kk], acc0);
                acc1 = fdot2f(wm16[1][kk], hk[kk], acc1);
            }
            float a0 = qsum(acc0);
            float a1 = qsum(acc1);
            if (ks == b) { z0 = a0; z1 = a1; }
        }
        *(h2*)&s_z16[ks][cM] = cvt2(gelu_ex(z0), gelu_ex(z1));
        __syncthreads();
        // ===== D: t2 = z @ w2_0 + b2 (octet) =====
#pragma unroll
        for (int b = 0; b < BC; b++) {
            const h8t* zp = (const h8t*)&s_z16[b][ks8 * 16];
            h8t zv0 = zp[0], zv1 = zp[1];
            h2 zk[8];
            unpack8(zv0, zk); unpack8(zv1, zk + 4);
            float acc0 = (ks8 == 0) ? h_b2[0] : 0.f;
            float acc1 = (ks8 == 0) ? h_b2[1] : 0.f;
#pragma unroll
            for (int kk = 0; kk < 8; kk++) {
                acc0 = fdot2f(ww16[0][kk], zk[kk], acc0);
                acc1 = fdot2f(ww16[1][kk], zk[kk], acc1);
            }
            float a0 = osum(acc0);
            float a1 = osum(acc1);
            if (ks8 == b) { s_t2[b][uD] = a0; s_t2[b][uD + 1] = a1; }
        }
        __syncthreads();
        // ===== E =====
        {
            const int bb = W;
            float v = s_t2[bb][lane];
            float m = redsum64(v) * (1.0f / 64.0f);
            float var = redsum64(v * v) * (1.0f / 64.0f) - m * m;
            float rs = rsqrtf(fmaxf(var, 0.0f) + 1e-5f);
            float a = (v - m) * rs * eLag + eLab;
            float hOld = (float)s_h16[bb][lane];
            float y = a + hOld;
            float m2 = redsum64(y) * (1.0f / 64.0f);
            float var2 = redsum64(y * y) * (1.0f / 64.0f) - m2 * m2;
            float rs2 = rsqrtf(fmaxf(var2, 0.0f) + 1e-5f);
            float h0n = (y - m2) * rs2 * eLog + eLob;
            s_h16[bb][lane] = (_Float16)h0n;
            float p = h0n + eRb0;
#pragma unroll
            for (int d = 0; d < 12; d++)
                p = fmaf(s_x[sl][bb][d], s_rw0[d * 64 + lane], p);
            s_buf[((size_t)bb * CT + tt) * 64 + lane] = (_Float16)p;   // LDS, not global
            if (tt + 1 < CT && lane < 12)
                s_x[sl ^ 1][W][lane] = px0 * (1.0f - pw) + px1 * pw;
        }
        __syncthreads();
    }
    {
        int b = tid >> 6, jj = tid & 63;
        gstate[((size_t)(sIdx * Bn + gbase + b)) * 256 + jj] = (float)s_h16[b][jj];
    }
    gstate[((size_t)(sIdx * Bn + gbase + ks)) * 256 + 64 + j] = cS;

    // coalesced dump: block's 8192 f16 of inp (layout matches exactly)
    {
        const size_t rowBase = ((size_t)(sIdx * Bn + gbase)) * CT;
        const h8t* srcp = (const h8t*)s_buf;
        h8t* dstp = (h8t*)(inp_w + rowBase * 64);
#pragma unroll
        for (int i = 0; i < 4; i++)
            dstp[tid + i * 256] = srcp[tid + i * 256];
    }
}

// ---------------------------------------------------------------------------
// Pass 2 body: layer 1 over a T-chunk. bid in [0,384).  Seed prefetch hoisted
// to the TOP of the timestep; merged output buffered in LDS, dumped at end.
// ---------------------------------------------------------------------------
__device__ __forceinline__ void pass2_body(
    int bid,
    const float* __restrict__ gw1,
    const float* __restrict__ M1g, const float* __restrict__ bias1g,
    const float* __restrict__ w2g, const float* __restrict__ b2g,
    const float* __restrict__ lag, const float* __restrict__ lab,
    const float* __restrict__ log_, const float* __restrict__ lob,
    const _Float16* __restrict__ G1Rr, float* __restrict__ gstate,
    unsigned short* __restrict__ merged_w,
    _Float16* __restrict__ s_buf, int t0) {
    const int tid = threadIdx.x;
    const int sIdx = bid >> 7;
    const int gbase = (bid & 127) * BC;
    const int W = tid >> 6, lane = tid & 63;
    const int q = lane >> 2, ks = lane & 3;
    const int oct = lane >> 3, ks8 = lane & 7;
    const int j = W * 16 + q;
    const int cM = W * 32 + q * 2;
    const int uD = W * 16 + oct * 2;

    __shared__ __align__(16) _Float16 p2_h16[BC][72];
    __shared__ __align__(16) _Float16 p2_ht16[BC][72];
    __shared__ __align__(16) _Float16 p2_z16[BC][136];
    __shared__ float p2_t2[BC][64];

    __builtin_amdgcn_s_setprio(1);   // recurrent chain = critical path

    const float* gw1s = gw1 + (size_t)sIdx * 128 * 256;
    h2 wg16[4][8], wm16[2][8], ww16[2][8];
#pragma unroll
    for (int g = 0; g < 4; g++)
#pragma unroll
        for (int kk = 0; kk < 8; kk++)
            wg16[g][kk] = cvt2(gw1s[(64 + ks * 16 + 2 * kk) * 256 + j + 64 * g],
                               gw1s[(64 + ks * 16 + 2 * kk + 1) * 256 + j + 64 * g]);
    const float* M1s = M1g + (sIdx * 2 + 1) * 8192;
#pragma unroll
    for (int cc = 0; cc < 2; cc++)
#pragma unroll
        for (int kk = 0; kk < 8; kk++)
            wm16[cc][kk] = cvt2(M1s[(ks * 16 + 2 * kk) * 128 + cM + cc],
                                M1s[(ks * 16 + 2 * kk + 1) * 128 + cM + cc]);
    const float* w2s = w2g + (sIdx * 2 + 1) * 8192;
#pragma unroll
    for (int cc = 0; cc < 2; cc++)
#pragma unroll
        for (int kk = 0; kk < 8; kk++)
            ww16[cc][kk] = cvt2(w2s[(ks8 * 16 + 2 * kk) * 64 + uD + cc],
                                w2s[(ks8 * 16 + 2 * kk + 1) * 64 + uD + cc]);

    float h_b1[2] = {bias1g[(sIdx * 2 + 1) * 128 + cM], bias1g[(sIdx * 2 + 1) * 128 + cM + 1]};
    float h_b2[2] = {b2g[(sIdx * 2 + 1) * 64 + uD], b2g[(sIdx * 2 + 1) * 64 + uD + 1]};
    int ei = (sIdx * 2 + 1) * 64 + lane;
    float eLag = lag[ei], eLab = lab[ei], eLog = log_[ei], eLob = lob[ei];

    {
        int b = tid >> 6, jj = tid & 63;
        float hv = (t0 == 0) ? 0.f : gstate[((size_t)(sIdx * Bn + gbase + b)) * 256 + 128 + jj];
        p2_h16[b][jj] = (_Float16)hv;
    }
    float cS = (t0 == 0) ? 0.f
                         : gstate[((size_t)(sIdx * Bn + gbase + ks)) * 256 + 192 + j];
    __syncthreads();

    const size_t rowBase = ((size_t)(sIdx * Bn + gbase)) * CT;
    const int pOff = W * 64 + lane;   // permuted gate-part position (contiguous per wave)
    unsigned short* s_mrg = (unsigned short*)s_buf;

    // prologue: seeds + residual for tt=0
    float g1rv[BC], rv;
#pragma unroll
    for (int b = 0; b < BC; b++)
        g1rv[b] = (float)G1Rr[(rowBase + (size_t)b * CT) * 320 + pOff];
    rv = (float)G1Rr[(rowBase + (size_t)W * CT) * 320 + 256 + lane];

    for (int tt = 0; tt < CT; tt++) {
        // hoisted prefetch of next timestep's seeds + residual: issued BEFORE
        // phase A so the gate compute covers their latency before the drain
        float g1rn[BC], rn;
        if (tt + 1 < CT) {
#pragma unroll
            for (int b = 0; b < BC; b++)
                g1rn[b] = (float)G1Rr[(rowBase + (size_t)b * CT + tt + 1) * 320 + pOff];
            rn = (float)G1Rr[(rowBase + (size_t)W * CT + tt + 1) * 320 + 256 + lane];
        } else {
#pragma unroll
            for (int b = 0; b < BC; b++) g1rn[b] = 0.f;
            rn = 0.f;
        }
        // ===== A =====
        float myF = 0, myI = 0, myG = 0, myO = 0;
#pragma unroll
        for (int b = 0; b < BC; b++) {
            const h8t* hp = (const h8t*)&p2_h16[b][ks * 16];
            h8t hv0 = hp[0], hv1 = hp[1];
            h2 hk[8];
            unpack8(hv0, hk); unpack8(hv1, hk + 4);
            float acc[4];
#pragma unroll
            for (int g = 0; g < 4; g++) acc[g] = (ks == g) ? g1rv[b] : 0.f;
#pragma unroll
            for (int kk = 0; kk < 8; kk++) {
#pragma unroll
                for (int g = 0; g < 4; g++)
                    acc[g] = fdot2f(wg16[g][kk], hk[kk], acc[g]);
            }
            float a0 = qsum(acc[0]);
            float a1 = qsum(acc[1]);
            float a2 = qsum(acc[2]);
            float a3 = qsum(acc[3]);
            if (ks == b) { myF = a0; myI = a1; myG = a2; myO = a3; }
        }
        {
            float cn = sigm(myF) * cS + sigm(myI) * tanhfast(myG);
            cS = cn;
            p2_ht16[ks][j] = (_Float16)(sigm(myO) * tanhfast(cn));
        }
        __syncthreads();
        // ===== C =====
        float z0 = 0, z1 = 0;
#pragma unroll
        for (int b = 0; b < BC; b++) {
            const h8t* hp = (const h8t*)&p2_ht16[b][ks * 16];
            h8t hv0 = hp[0], hv1 = hp[1];
            h2 hk[8];
            unpack8(hv0, hk); unpack8(hv1, hk + 4);
            float acc0 = (ks == 0) ? h_b1[0] : 0.f;
            float acc1 = (ks == 0) ? h_b1[1] : 0.f;
#pragma unroll
            for (int kk = 0; kk < 8; kk++) {
                acc0 = fdot2f(wm16[0][kk], hk[kk], acc0);
                acc1 = fdot2f(wm16[1][kk], hk[kk], acc1);
            }
            float a0 = qsum(acc0);
            float a1 = qsum(acc1);
            if (ks == b) { z0 = a0; z1 = a1; }
        }
        *(h2*)&p2_z16[ks][cM] = cvt2(gelu_ex(z0), gelu_ex(z1));
        __syncthreads();
        // ===== D =====
#pragma unroll
        for (int b = 0; b < BC; b++) {
            const h8t* zp = (const h8t*)&p2_z16[b][ks8 * 16];
            h8t zv0 = zp[0], zv1 = zp[1];
            h2 zk[8];
            unpack8(zv0, zk); unpack8(zv1, zk + 4);
            float acc0 = (ks8 == 0) ? h_b2[0] : 0.f;
            float acc1 = (ks8 == 0) ? h_b2[1] : 0.f;
#pragma unroll
            for (int kk = 0; kk < 8; kk++) {
                acc0 = fdot2f(ww16[0][kk], zk[kk], acc0);
                acc1 = fdot2f(ww16[1][kk], zk[kk], acc1);
            }
            float a0 = osum(acc0);
            float a1 = osum(acc1);
            if (ks8 == b) { p2_t2[b][uD] = a0; p2_t2[b][uD + 1] = a1; }
        }
        __syncthreads();
        // ===== E =====
        {
            const int bb = W;
            float v = p2_t2[bb][lane];
            float m = redsum64(v) * (1.0f / 64.0f);
            float var = redsum64(v * v) * (1.0f / 64.0f) - m * m;
            float rs = rsqrtf(fmaxf(var, 0.0f) + 1e-5f);
            float a = (v - m) * rs * eLag + eLab;
            float hOld = (float)p2_h16[bb][lane];
            float y = a + hOld;
            float m2 = redsum64(y) * (1.0f / 64.0f);
            float var2 = redsum64(y * y) * (1.0f / 64.0f) - m2 * m2;
            float rs2 = rsqrtf(fmaxf(var2, 0.0f) + 1e-5f);
            float h1n = (y - m2) * rs2 * eLog + eLob;
            p2_h16[bb][lane] = (_Float16)h1n;
            s_mrg[((size_t)bb * CT + tt) * 64 + lane] = f2u(h1n + rv);   // LDS, not global
        }
        __syncthreads();
#pragma unroll
        for (int b = 0; b < BC; b++) g1rv[b] = g1rn[b];
        rv = rn;
    }
    {
        int b = tid >> 6, jj = tid & 63;
        gstate[((size_t)(sIdx * Bn + gbase + b)) * 256 + 128 + jj] = (float)p2_h16[b][jj];
    }
    gstate[((size_t)(sIdx * Bn + gbase + ks)) * 256 + 192 + j] = cS;

    // coalesced dump: block's 8192 bf16 of merged
    {
        const h8t* srcp = (const h8t*)s_mrg;
        h8t* dstp = (h8t*)(merged_w + rowBase * 64);
#pragma unroll
        for (int i = 0; i < 4; i++)
            dstp[tid + i * 256] = srcp[tid + i * 256];
    }
}

// ---------------------------------------------------------------------------
// g1r body: bid in [0,258). Reads inp (f16) from prev launch, writes G1R (f16).
// f16 dot2 with pre-packed permuted weights; LDS tile stores input k-pairs.
// ---------------------------------------------------------------------------
__device__ __forceinline__ void g1r_body(
    int bid,
    const h2* __restrict__ gw1p16, const float* __restrict__ gb1p,
    const h2* __restrict__ rw1p16, const float* __restrict__ rb1,
    const _Float16* __restrict__ inp_r, _Float16* __restrict__ G1Rw) {
    const int tid = threadIdx.x;
    const int s = bid / 86;
    const int bb = bid % 86;
    __shared__ __align__(16) h2 s_in2[32][36];   // [k-pair][row]

    const int c4 = tid & 63, rg = tid >> 6;
    float4 bias = *(const float4*)(gb1p + s * 256 + c4 * 4);
    float rbias = rb1[s * 64 + c4];
    const h2* Wg = gw1p16 + (size_t)s * 32 * 256;
    const h2* Wr = rw1p16 + (size_t)s * 32 * 64;

    const size_t sRow = (size_t)s * Bn * CT;
    for (int tile = 0; tile < 6; tile++) {
        int tIdx = bb * 6 + tile;
        if (tIdx >= 512) break;
        int r0 = tIdx * 32;
        __syncthreads();
        for (int i = tid; i < 512; i += 256) {
            int r = i >> 4, kq = i & 15;
            h4 v = *(const h4*)(inp_r + (sRow + r0 + r) * 64 + kq * 4);
            s_in2[kq * 2 + 0][r] = mk2(v.x, v.y);
            s_in2[kq * 2 + 1][r] = mk2(v.z, v.w);
        }
        __syncthreads();
        float acc[8][4], accR[8];
#pragma unroll
        for (int r = 0; r < 8; r++) {
            acc[r][0] = bias.x; acc[r][1] = bias.y; acc[r][2] = bias.z; acc[r][3] = bias.w;
            accR[r] = rbias;
        }
#pragma unroll 4
        for (int k2 = 0; k2 < 32; k2++) {
            h8t wv = *(const h8t*)(Wg + (size_t)k2 * 256 + c4 * 4);
            h2 wp[4]; unpack8(wv, wp);
            h2 wR = Wr[k2 * 64 + c4];
            const h8t* ip = (const h8t*)&s_in2[k2][rg * 8];
            h8t iv0 = ip[0], iv1 = ip[1];
            h2 in2[8]; unpack8(iv0, in2); unpack8(iv1, in2 + 4);
#pragma unroll
            for (int r = 0; r < 8; r++) {
                acc[r][0] = fdot2f(in2[r], wp[0], acc[r][0]);
                acc[r][1] = fdot2f(in2[r], wp[1], acc[r][1]);
                acc[r][2] = fdot2f(in2[r], wp[2], acc[r][2]);
                acc[r][3] = fdot2f(in2[r], wp[3], acc[r][3]);
                accR[r] = fdot2f(in2[r], wR, accR[r]);
            }
        }
#pragma unroll
        for (int r = 0; r < 8; r++) {
            size_t row = sRow + r0 + rg * 8 + r;
            h4 o;
            o.x = (_Float16)acc[r][0]; o.y = (_Float16)acc[r][1];
            o.z = (_Float16)acc[r][2]; o.w = (_Float16)acc[r][3];
            *(h4*)(G1Rw + row * 320 + c4 * 4) = o;
            G1Rw[row * 320 + 256 + c4] = (_Float16)accR[r];
        }
    }
}

// ---------------------------------------------------------------------------
// combine body: bid in [0,512); each wave handles 8 (b,t) rows
// ---------------------------------------------------------------------------
__device__ __forceinline__ void combine_body(
    int bid,
    const unsigned short* __restrict__ merged_r,
    const float* __restrict__ attn_w,
    void* __restrict__ outv, const int* __restrict__ flag, int t0) {
    int W = threadIdx.x >> 6, lane = threadIdx.x & 63;
    float aw = attn_w[lane];
    size_t stride = (size_t)Bn * CT * 64;
    int isf = *flag;
#pragma unroll
    for (int r = 0; r < 8; r++) {
        int wid = (bid * 4 + W) * 8 + r;
        int b = wid >> 5, tt = wid & 31;
        size_t base = (((size_t)b) * CT + tt) * 64 + lane;
        float m0 = u2f(merged_r[base]);
        float m1 = u2f(merged_r[base + stride]);
        float m2 = u2f(merged_r[base + 2 * stride]);
        float e0 = redsum64(m0 * aw);
        float e1 = redsum64(m1 * aw);
        float e2 = redsum64(m2 * aw);
        float mx = fmaxf(e0, fmaxf(e1, e2));
        float x0 = expf(e0 - mx), x1 = expf(e1 - mx), x2 = expf(e2 - mx);
        float inv = 1.0f / (x0 + x1 + x2);
        float val = (x0 * m0 + x1 * m1 + x2 * m2) * inv;
        size_t ob = (((size_t)b) * Ln + t0 + tt) * 64 + lane;
        if (isf) ((float*)outv)[ob] = val;
        else ((unsigned short*)outv)[ob] = f2u(val);
    }
}

// ---------------------------------------------------------------------------
// Mega kernel: software-pipelined stages, all deps come from the PREVIOUS
// launch.  Launch m: pass1(m) | g1r(m-1) | pass2(m-2) | combine(m-3).
// s_scratch (16KB) is the per-timestep output buffer, overlaid between
// pass1 (inp) and pass2 (merged) roles.  LDS/block ~31KB -> 5 blocks/CU
// (matches the waves_per_eu(2,5) cap; 5*31.2KB = 156KB <= 160KB).
// ---------------------------------------------------------------------------
__global__ __launch_bounds__(256) __attribute__((amdgpu_waves_per_eu(2, 5)))
void mega_kernel(
    const float* __restrict__ x, const float* __restrict__ gw0,
    const float* __restrict__ gb0, const float* __restrict__ gw1,
    const h2* __restrict__ gw1p16, const float* __restrict__ gb1p,
    const h2* __restrict__ rw1p16,
    const float* __restrict__ M1g, const float* __restrict__ bias1g,
    const float* __restrict__ w2g, const float* __restrict__ b2g,
    const float* __restrict__ lag, const float* __restrict__ lab,
    const float* __restrict__ log_, const float* __restrict__ lob,
    const float* __restrict__ rw0, const float* __restrict__ rb0,
    const float* __restrict__ rb1,
    float* __restrict__ gstate,
    _Float16* __restrict__ inpB, _Float16* __restrict__ G1RB,
    unsigned short* __restrict__ mergedB,
    const float* __restrict__ attn_w, void* __restrict__ outv,
    const int* __restrict__ flag,
    int c_p1, int c_g1r, int c_p2, int c_comb) {
    __shared__ __align__(16) _Float16 s_scratch[(size_t)BC * CT * 64];
    int bid = blockIdx.x;
    if (bid < P1OFF) {
        if (c_p2 >= 0) {
            const _Float16* g1r_r = G1RB + (size_t)(c_p2 & 1) * NG1R;
            unsigned short* merged_w = mergedB + (size_t)(c_p2 & 1) * NMERG;
            pass2_body(bid, gw1, M1g, bias1g, w2g, b2g, lag, lab, log_, lob,
                       g1r_r, gstate, merged_w, s_scratch, c_p2 * CT);
        }
    } else if (bid < GROFF) {
        if (c_p1 >= 0) {
            _Float16* inp_w = inpB + (size_t)(c_p1 & 1) * NINP;
            pass1_body(bid - P1OFF, x, gw0, gb0, M1g, bias1g, w2g, b2g,
                       lag, lab, log_, lob, rw0, rb0, gstate, inp_w,
                       s_scratch, c_p1 * CT);
        }
    } else if (bid < CBOFF) {
        if (c_g1r >= 0) {
            const _Float16* inp_r = inpB + (size_t)(c_g1r & 1) * NINP;
            _Float16* g1r_w = G1RB + (size_t)(c_g1r & 1) * NG1R;
            g1r_body(bid - GROFF, gw1p16, gb1p, rw1p16, rb1, inp_r, g1r_w);
        }
    } else {
        if (c_comb >= 0) {
            const unsigned short* merged_r = mergedB + (size_t)(c_comb & 1) * NMERG;
            combine_body(bid - CBOFF, merged_r, attn_w, outv, flag, c_comb * CT);
        }
    }
}

extern "C" void kernel_launch(void* const* d_in, const int* in_sizes, int n_in,
                              void* d_out, int out_size, void* d_ws, size_t ws_size,
                              hipStream_t stream) {
    (void)out_size; (void)ws_size;
    int* flag = (int*)d_ws;
    float* canon = (float*)((char*)d_ws + 16);

    ConvArgs ca;
    size_t tot = 0;
    unsigned nblocks = 0;
    for (int i = 0; i < NIN; i++) {
        ca.src[i] = d_in[i];
        ca.dstOff[i] = (unsigned)tot;
        unsigned n = (unsigned)in_sizes[i];
        ca.n[i] = n;
        ca.blockStart[i] = nblocks;
        nblocks += (n + 2047) / 2048;
        tot += n;
    }
    ca.blockStart[NIN] = nblocks;

    size_t canonBytes = (tot * 4 + 15) & ~(size_t)15;
    char* p = (char*)d_ws + 16 + canonBytes;
    float* M1 = (float*)p;       p += (size_t)3 * 2 * 64 * 128 * 4;
    float* bias1 = (float*)p;    p += (size_t)3 * 2 * 128 * 4;
    float* gb1p = (float*)p;     p += (size_t)3 * 256 * 4;
    h2* gw1p16 = (h2*)p;         p += (size_t)3 * 32 * 256 * 4;   // h2 = 4B
    h2* rw1p16 = (h2*)p;         p += (size_t)3 * 32 * 64 * 4;
    float* gstate = (float*)p;   p += (size_t)3 * 512 * 256 * 4;
    p = (char*)(((uintptr_t)p + 15) & ~(uintptr_t)15);
    _Float16* inpB = (_Float16*)p;      p += 2 * NINP * 2;
    _Float16* G1RB = (_Float16*)p;      p += 2 * NG1R * 2;
    p = (char*)(((uintptr_t)p + 15) & ~(uintptr_t)15);
    unsigned short* mergedB = (unsigned short*)p;   // 2 * NMERG * 2 bytes

    const float* x    = canon + ca.dstOff[0];
    const float* gw0  = canon + ca.dstOff[1];
    const float* gb0  = canon + ca.dstOff[2];
    const float* gw1  = canon + ca.dstOff[3];
    const float* gb1  = canon + ca.dstOff[4];
    const float* mi_w = canon + ca.dstOff[5];
    const float* mi_b = canon + ca.dstOff[6];
    const float* mo_w = canon + ca.dstOff[7];
    const float* mo_b = canon + ca.dstOff[8];
    const float* w1   = canon + ca.dstOff[9];
    const float* b1   = canon + ca.dstOff[10];
    const float* w2   = canon + ca.dstOff[11];
    const float* b2   = canon + ca.dstOff[12];
    const float* lag  = canon + ca.dstOff[13];
    const float* lab  = canon + ca.dstOff[14];
    const float* log_ = canon + ca.dstOff[15];
    const float* lob  = canon + ca.dstOff[16];
    const float* rw0  = canon + ca.dstOff[17];
    const float* rb0  = canon + ca.dstOff[18];
    const float* rw1  = canon + ca.dstOff[19];
    const float* rb1  = canon + ca.dstOff[20];
    const float* attn_w = canon + ca.dstOff[21];

    convert_kernel<<<dim3(nblocks), dim3(256), 0, stream>>>(ca, canon);
    setup_kernel<<<dim3(10), dim3(256), 0, stream>>>(
        (const unsigned short*)d_in[0], flag,
        mi_w, mi_b, mo_w, mo_b, w1, b1, M1, bias1,
        gw1, gb1, rw1, gw1p16, gb1p, rw1p16);

    // software pipeline: launch m runs pass1(m), g1r(m-1), pass2(m-2), combine(m-3)
    for (int m = 0; m <= NCHUNK + 2; m++) {
        int c1 = (m < NCHUNK) ? m : -1;
        int cg = (m - 1 >= 0 && m - 1 < NCHUNK) ? m - 1 : -1;
        int c2 = (m - 2 >= 0 && m - 2 < NCHUNK) ? m - 2 : -1;
        int cc = (m - 3 >= 0 && m - 3 < NCHUNK) ? m - 3 : -1;
        mega_kernel<<<dim3(MEGABLK), dim3(256), 0, stream>>>(
            x, gw0, gb0, gw1, gw1p16, gb1p, rw1p16, M1, bias1, w2, b2,
            lag, lab, log_, lob, rw0, rb0, rb1, gstate, inpB, G1RB, mergedB,
            attn_w, d_out, flag, c1, cg, c2, cc);
    }
}

// Round 12
// 2988.334 us; speedup vs baseline: 1.0289x; 1.0289x over previous
//
#include <hip/hip_runtime.h>
#include <hip/hip_bf16.h>
#include <math.h>

// Problem constants
#define Sn 3
#define Hn 64
#define Dn 12
#define Bn 512
#define Ln 512
#define BC 4            // batch elems per workgroup (one per wave for E-phase)
#define IN0 76          // D + H
#define NIN 22
#define CT 64           // timesteps per chunk (halves launch count vs 32)
#define NCHUNK (Ln / CT)
#define GTILES (Bn * CT / 32)   // g1r tiles per scale
// mega grid layout: [0,384) pass2 | [384,768) pass1 | [768,1026) g1r | [1026,1538) combine
#define P2OFF 0
#define P1OFF 384
#define GROFF 768
#define CBOFF 1026
#define MEGABLK 1538

// double-buffered intermediate sizes (elements)
#define NINP ((size_t)3 * Bn * CT * 64)     // f16
#define NG1R ((size_t)3 * Bn * CT * 320)    // f16
#define NMERG ((size_t)3 * Bn * CT * 64)    // bf16 (ushort)

using bf16 = __hip_bfloat16;
typedef _Float16 h2 __attribute__((ext_vector_type(2)));
typedef _Float16 h4 __attribute__((ext_vector_type(4)));
typedef _Float16 h8t __attribute__((ext_vector_type(8)));
typedef int i2v __attribute__((ext_vector_type(2)));

__device__ __forceinline__ float u2f(unsigned short x) {
    return __uint_as_float(((unsigned int)x) << 16);
}
__device__ __forceinline__ unsigned short f2u(float f) {
    bf16 h = __float2bfloat16(f);
    unsigned short u;
    __builtin_memcpy(&u, &h, 2);
    return u;
}

// ---- fast transcendentals (exact algebraic forms on v_exp_f32 / v_rcp_f32) ----
__device__ __forceinline__ float ex2(float x) {
#if __has_builtin(__builtin_amdgcn_exp2f)
    return __builtin_amdgcn_exp2f(x);
#else
    return exp2f(x);
#endif
}
__device__ __forceinline__ float frcp(float x) {
#if __has_builtin(__builtin_amdgcn_rcpf)
    return __builtin_amdgcn_rcpf(x);
#else
    return 1.0f / x;
#endif
}
__device__ __forceinline__ float sigm(float x) {
    return frcp(1.0f + ex2(-1.44269504f * x));
}
__device__ __forceinline__ float tanhfast(float x) {
    // tanh(x) = 1 - 2/(exp(2x)+1); exp(2x) = exp2(2.885390x). Saturates correctly.
    return 1.0f - 2.0f * frcp(1.0f + ex2(2.88539008f * x));
}
__device__ __forceinline__ float gelu_ex(float x) { return 0.5f * x * (1.0f + erff(x * 0.70710678118654752f)); }

// ---- f16 dot2 helpers (v_dot2_f32_f16: 2 MACs/instr, fp32 accumulate) ----
__device__ __forceinline__ float fdot2f(h2 a, h2 b, float c) {
#if __has_builtin(__builtin_amdgcn_fdot2)
    return __builtin_amdgcn_fdot2(a, b, c, false);
#else
    return fmaf((float)a.x, (float)b.x, fmaf((float)a.y, (float)b.y, c));
#endif
}
__device__ __forceinline__ h2 cvt2(float x, float y) {
    h2 r; r.x = (_Float16)x; r.y = (_Float16)y; return r;
}
__device__ __forceinline__ h2 mk2(_Float16 a, _Float16 b) {
    h2 r; r.x = a; r.y = b; return r;
}
__device__ __forceinline__ void unpack8(h8t v, h2* out) {
    out[0] = __builtin_shufflevector(v, v, 0, 1);
    out[1] = __builtin_shufflevector(v, v, 2, 3);
    out[2] = __builtin_shufflevector(v, v, 4, 5);
    out[3] = __builtin_shufflevector(v, v, 6, 7);
}

// ---- cross-lane reductions (pure VALU/DPP where gfx950 allows) ----
template <int CTRL>
__device__ __forceinline__ float qp(float v) {
    return __int_as_float(__builtin_amdgcn_update_dpp(0, __float_as_int(v), CTRL, 0xF, 0xF, true));
}
__device__ __forceinline__ float qsum(float v) {
    v += qp<0xB1>(v);   // xor1 (quad perm)
    v += qp<0x4E>(v);   // xor2
    return v;
}
// 8-lane (octet) sum: after qsum v is quad-uniform, so row_half_mirror
// (mirror within 8) fetches the other quad's sum -> no LDS op.
__device__ __forceinline__ float osum(float v) {
    v = qsum(v);
    v += qp<0x141>(v);  // half_mirror: cross-quad within octet
    return v;
}
__device__ __forceinline__ float xadd16(float v) {
#if __has_builtin(__builtin_amdgcn_permlane16_swap)
    i2v r = __builtin_amdgcn_permlane16_swap(__float_as_int(v), __float_as_int(v), false, false);
    return __int_as_float(r.x) + __int_as_float(r.y);
#else
    return v + __int_as_float(__builtin_amdgcn_ds_swizzle(__float_as_int(v), 0x401F));
#endif
}
__device__ __forceinline__ float xadd32(float v) {
#if __has_builtin(__builtin_amdgcn_permlane32_swap)
    i2v r = __builtin_amdgcn_permlane32_swap(__float_as_int(v), __float_as_int(v), false, false);
    return __int_as_float(r.x) + __int_as_float(r.y);
#else
    return v + __shfl_xor(v, 32, 64);
#endif
}
// full-wave sum: 4 DPP + 2 permlane swaps — zero LDS-pipe ops
__device__ __forceinline__ float redsum64(float v) {
    v += qp<0xB1>(v);
    v += qp<0x4E>(v);
    v += qp<0x141>(v);
    v += qp<0x140>(v);
    v = xadd16(v);
    v = xadd32(v);
    return v;
}

// ---------------------------------------------------------------------------
// canonicalize all inputs to fp32 in ws.  Each block recomputes the dtype
// decision locally from the (L2-resident) first 2048 halfwords of x.
// ---------------------------------------------------------------------------
struct ConvArgs {
    const void* src[NIN];
    unsigned dstOff[NIN];
    unsigned n[NIN];
    unsigned blockStart[NIN + 1];
};

__global__ __launch_bounds__(256) void convert_kernel(ConvArgs a, float* __restrict__ dst) {
    __shared__ int sh[4];
    int tid = threadIdx.x;
    const unsigned short* xr = (const unsigned short*)a.src[0];
    int cnt = 0;
    for (int ii = tid; ii < 2048; ii += 256) {
        unsigned e = (xr[ii] >> 7) & 0xFF;
        if (e >= 110 && e <= 133) cnt++;
    }
    for (int o = 32; o > 0; o >>= 1) cnt += __shfl_xor(cnt, o, 64);
    if ((tid & 63) == 0) sh[tid >> 6] = cnt;
    __syncthreads();
    bool isf32 = (sh[0] + sh[1] + sh[2] + sh[3]) < 1640;

    int bid = blockIdx.x;
    int i = 0;
    while (i < NIN - 1 && bid >= (int)a.blockStart[i + 1]) i++;
    unsigned lb = (unsigned)bid - a.blockStart[i];
    unsigned base = lb * 2048 + tid;
    unsigned n = a.n[i];
    float* d = dst + a.dstOff[i];
    const float* sf = (const float*)a.src[i];
    const unsigned short* su = (const unsigned short*)a.src[i];
#pragma unroll
    for (int e = 0; e < 8; e++) {
        unsigned idx = base + e * 256;
        if (idx < n) d[idx] = isf32 ? sf[idx] : u2f(su[idx]);
    }
}

// ---------------------------------------------------------------------------
// Setup (one launch, 10 blocks): fuse | perm | dtype flag
// ---------------------------------------------------------------------------
__global__ __launch_bounds__(256) void setup_kernel(
    const unsigned short* __restrict__ xr, int* __restrict__ flag,
    const float* __restrict__ mi_w, const float* __restrict__ mi_b,
    const float* __restrict__ mo_w, const float* __restrict__ mo_b,
    const float* __restrict__ w1, const float* __restrict__ b1,
    float* __restrict__ M1out, float* __restrict__ bias1out,
    const float* __restrict__ gw1, const float* __restrict__ gb1,
    const float* __restrict__ rw1,
    h2* __restrict__ gw1p16, float* __restrict__ gb1p,
    h2* __restrict__ rw1p16) {
    int bid = blockIdx.x;
    int tid = threadIdx.x;
    if (bid < 6) {
        int sl = bid;
        __shared__ float T[64][64];
        __shared__ float bT[64];
        const float* Mv = mi_w + sl * 64 * 192;
        const float* Mo = mo_w + sl * 64 * 64;
        for (int idx = tid; idx < 64 * 64; idx += 256) {
            int k = idx >> 6, n = idx & 63;
            float acc = 0.f;
            for (int j = 0; j < 64; j++) acc += Mv[k * 192 + 128 + j] * Mo[j * 64 + n];
            T[k][n] = acc;
        }
        for (int n = tid; n < 64; n += 256) {
            float acc = mo_b[sl * 64 + n];
            for (int j = 0; j < 64; j++) acc += mi_b[sl * 192 + 128 + j] * Mo[j * 64 + n];
            bT[n] = acc;
        }
        __syncthreads();
        const float* W1 = w1 + sl * 64 * 128;
        for (int idx = tid; idx < 64 * 128; idx += 256) {
            int k = idx >> 7, m = idx & 127;
            float acc = 0.f;
            for (int n = 0; n < 64; n++) acc += T[k][n] * W1[n * 128 + m];
            M1out[sl * 64 * 128 + idx] = acc;
        }
        for (int m = tid; m < 128; m += 256) {
            float acc = b1[sl * 128 + m];
            for (int n = 0; n < 64; n++) acc += bT[n] * W1[n * 128 + m];
            bias1out[sl * 128 + m] = acc;
        }
    } else if (bid < 9) {
        int s = bid - 6;
        const float* G = gw1 + (size_t)s * 128 * 256;
        for (int idx = tid; idx < 32 * 256; idx += 256) {
            int k2 = idx >> 8, p = idx & 255;
            int c = (p & 3) * 64 + ((p >> 6) << 4) + ((p >> 2) & 15);
            gw1p16[((size_t)s * 32 + k2) * 256 + p] =
                cvt2(G[(2 * k2) * 256 + c], G[(2 * k2 + 1) * 256 + c]);
        }
        for (int p = tid; p < 256; p += 256) {
            int c = (p & 3) * 64 + ((p >> 6) << 4) + ((p >> 2) & 15);
            gb1p[s * 256 + p] = gb1[s * 256 + c];
        }
        const float* R = rw1 + (size_t)s * 64 * 64;
        for (int idx = tid; idx < 32 * 64; idx += 256) {
            int k2 = idx >> 6, c = idx & 63;
            rw1p16[((size_t)s * 32 + k2) * 64 + c] =
                cvt2(R[(2 * k2) * 64 + c], R[(2 * k2 + 1) * 64 + c]);
        }
    } else {
        __shared__ int sh[4];
        int cnt = 0;
        for (int ii = tid; ii < 2048; ii += 256) {
            unsigned e = (xr[ii] >> 7) & 0xFF;
            if (e >= 110 && e <= 133) cnt++;
        }
        for (int o = 32; o > 0; o >>= 1) cnt += __shfl_xor(cnt, o, 64);
        if ((tid & 63) == 0) sh[tid >> 6] = cnt;
        __syncthreads();
        if (tid == 0) {
            int tot = sh[0] + sh[1] + sh[2] + sh[3];
            *flag = (tot < 1640) ? 1 : 0;
        }
    }
}

// ---------------------------------------------------------------------------
// Pass 1 body: layer 0 over a T-chunk. bid in [0,384). Writes inp chunk (f16).
// ---------------------------------------------------------------------------
__device__ __forceinline__ void pass1_body(
    int bid,
    const float* __restrict__ x, const float* __restrict__ gw0,
    const float* __restrict__ gb0,
    const float* __restrict__ M1g, const float* __restrict__ bias1g,
    const float* __restrict__ w2g, const float* __restrict__ b2g,
    const float* __restrict__ lag, const float* __restrict__ lab,
    const float* __restrict__ log_, const float* __restrict__ lob,
    const float* __restrict__ rw0, const float* __restrict__ rb0,
    float* __restrict__ gstate, _Float16* __restrict__ inp_w, int t0) {
    const int tid = threadIdx.x;
    const int sIdx = bid >> 7;
    const int gbase = (bid & 127) * BC;
    const int W = tid >> 6, lane = tid & 63;
    const int q = lane >> 2, ks = lane & 3;
    const int oct = lane >> 3, ks8 = lane & 7;
    const int j = W * 16 + q;
    const int cM = W * 32 + q * 2;
    const int uD = W * 16 + oct * 2;

    const int Li = (sIdx == 0) ? 170 : (sIdx == 1 ? 512 : 256);
    const int st = (sIdx == 0) ? 342 : (sIdx == 1 ? 0 : 256);
    const float sc = (float)Li / 512.0f;

    __shared__ float s_x[2][BC][12];
    __shared__ __align__(16) _Float16 s_h16[BC][72];    // 144B rows: bank-shift 4
    __shared__ __align__(16) _Float16 s_ht16[BC][72];
    __shared__ __align__(16) _Float16 s_z16[BC][136];   // 272B rows
    __shared__ float s_t2[BC][64];
    __shared__ float s_rw0[768];

    __builtin_amdgcn_s_setprio(1);   // recurrent chain = critical path

    const float* gw0s = gw0 + sIdx * IN0 * 256;
    float wx[12];
    h2 wg16[4][8], wm16[2][8], ww16[2][8];
#pragma unroll
    for (int g = 0; g < 4; g++)
#pragma unroll
        for (int d = 0; d < 3; d++) wx[g * 3 + d] = gw0s[(ks * 3 + d) * 256 + j + 64 * g];
#pragma unroll
    for (int g = 0; g < 4; g++)
#pragma unroll
        for (int kk = 0; kk < 8; kk++)
            wg16[g][kk] = cvt2(gw0s[(12 + ks * 16 + 2 * kk) * 256 + j + 64 * g],
                               gw0s[(12 + ks * 16 + 2 * kk + 1) * 256 + j + 64 * g]);
    const float* M1s = M1g + (sIdx * 2 + 0) * 8192;
#pragma unroll
    for (int cc = 0; cc < 2; cc++)
#pragma unroll
        for (int kk = 0; kk < 8; kk++)
            wm16[cc][kk] = cvt2(M1s[(ks * 16 + 2 * kk) * 128 + cM + cc],
                                M1s[(ks * 16 + 2 * kk + 1) * 128 + cM + cc]);
    const float* w2s = w2g + (sIdx * 2 + 0) * 8192;
#pragma unroll
    for (int cc = 0; cc < 2; cc++)
#pragma unroll
        for (int kk = 0; kk < 8; kk++)
            ww16[cc][kk] = cvt2(w2s[(ks8 * 16 + 2 * kk) * 64 + uD + cc],
                                w2s[(ks8 * 16 + 2 * kk + 1) * 64 + uD + cc]);

    float h_gb[4];
#pragma unroll
    for (int g = 0; g < 4; g++) h_gb[g] = gb0[sIdx * 256 + j + 64 * g];
    float h_b1[2] = {bias1g[(sIdx * 2 + 0) * 128 + cM], bias1g[(sIdx * 2 + 0) * 128 + cM + 1]};
    float h_b2[2] = {b2g[(sIdx * 2 + 0) * 64 + uD], b2g[(sIdx * 2 + 0) * 64 + uD + 1]};
    int ei = (sIdx * 2 + 0) * 64 + lane;
    float eLag = lag[ei], eLab = lab[ei], eLog = log_[ei], eLob = lob[ei];
    float eRb0 = rb0[sIdx * 64 + lane];

    for (int i = tid; i < 768; i += 256) s_rw0[i] = rw0[sIdx * 768 + i];
    {
        int b = tid >> 6, jj = tid & 63;
        float hv = (t0 == 0) ? 0.f : gstate[((size_t)(sIdx * Bn + gbase + b)) * 256 + jj];
        s_h16[b][jj] = (_Float16)hv;
    }
    float cS = (t0 == 0) ? 0.f
                         : gstate[((size_t)(sIdx * Bn + gbase + ks)) * 256 + 64 + j];
    if (tid < BC * 12) {
        int b = tid / 12, d = tid % 12;
        float srcp = fmaxf((t0 + 0.5f) * sc - 0.5f, 0.f);
        int i0 = (int)floorf(srcp); if (i0 > Li - 1) i0 = Li - 1;
        int i1 = i0 + 1; if (i1 > Li - 1) i1 = Li - 1;
        float w = srcp - (float)i0;
        int gb = gbase + b;
        s_x[0][b][d] = x[(gb * Ln + st + i0) * 12 + d] * (1.0f - w) + x[(gb * Ln + st + i1) * 12 + d] * w;
    }
    __syncthreads();

    for (int tt = 0; tt < CT; tt++) {
        const int sl = tt & 1;
        // ===== A: gates0 + cell =====
        float myF = 0, myI = 0, myG = 0, myO = 0;
#pragma unroll
        for (int b = 0; b < BC; b++) {
            const h8t* hp = (const h8t*)&s_h16[b][ks * 16];
            h8t hv0 = hp[0], hv1 = hp[1];
            h2 hk[8];
            unpack8(hv0, hk); unpack8(hv1, hk + 4);
            float x0 = s_x[sl][b][ks * 3], x1 = s_x[sl][b][ks * 3 + 1], x2 = s_x[sl][b][ks * 3 + 2];
            float acc[4];
#pragma unroll
            for (int g = 0; g < 4; g++) {
                float s0 = (ks == 0) ? h_gb[g] : 0.f;
                acc[g] = fmaf(wx[g * 3], x0, fmaf(wx[g * 3 + 1], x1, fmaf(wx[g * 3 + 2], x2, s0)));
            }
#pragma unroll
            for (int kk = 0; kk < 8; kk++) {
#pragma unroll
                for (int g = 0; g < 4; g++)
                    acc[g] = fdot2f(wg16[g][kk], hk[kk], acc[g]);
            }
            float a0 = qsum(acc[0]);
            float a1 = qsum(acc[1]);
            float a2 = qsum(acc[2]);
            float a3 = qsum(acc[3]);
            if (ks == b) { myF = a0; myI = a1; myG = a2; myO = a3; }
        }
        {
            float cn = sigm(myF) * cS + sigm(myI) * tanhfast(myG);
            cS = cn;
            s_ht16[ks][j] = (_Float16)(sigm(myO) * tanhfast(cn));
        }
        __syncthreads();
        // ===== C: z = gelu(ht @ M1_0 + bias1) =====
        float z0 = 0, z1 = 0;
#pragma unroll
        for (int b = 0; b < BC; b++) {
            const h8t* hp = (const h8t*)&s_ht16[b][ks * 16];
            h8t hv0 = hp[0], hv1 = hp[1];
            h2 hk[8];
            unpack8(hv0, hk); unpack8(hv1, hk + 4);
            float acc0 = (ks == 0) ? h_b1[0] : 0.f;
            float acc1 = (ks == 0) ? h_b1[1] : 0.f;
#pragma unroll
            for (int kk = 0; kk < 8; kk++) {
                acc0 = fdot2f(wm16[0][kk], hk[kk], acc0);
                acc1 = fdot2f(wm16[1][kk], hk[kk], acc1);
            }
            float a0 = qsum(acc0);
            float a1 = qsum(acc1);
            if (ks == b) { z0 = a0; z1 = a1; }
        }
        *(h2*)&s_z16[ks][cM] = cvt2(gelu_ex(z0), gelu_ex(z1));
        __syncthreads();
        // ===== D: t2 = z @ w2_0 + b2 (octet) =====
#pragma unroll
        for (int b = 0; b < BC; b++) {
            const h8t* zp = (const h8t*)&s_z16[b][ks8 * 16];
            h8t zv0 = zp[0], zv1 = zp[1];
            h2 zk[8];
            unpack8(zv0, zk); unpack8(zv1, zk + 4);
            float acc0 = (ks8 == 0) ? h_b2[0] : 0.f;
            float acc1 = (ks8 == 0) ? h_b2[1] : 0.f;
#pragma unroll
            for (int kk = 0; kk < 8; kk++) {
                acc0 = fdot2f(ww16[0][kk], zk[kk], acc0);
                acc1 = fdot2f(ww16[1][kk], zk[kk], acc1);
            }
            float a0 = osum(acc0);
            float a1 = osum(acc1);
            if (ks8 == b) { s_t2[b][uD] = a0; s_t2[b][uD + 1] = a1; }
        }
        __syncthreads();
        // ===== E =====
        {
            const int bb = W;
            float v = s_t2[bb][lane];
            float m = redsum64(v) * (1.0f / 64.0f);
            float var = redsum64(v * v) * (1.0f / 64.0f) - m * m;
            float rs = rsqrtf(fmaxf(var, 0.0f) + 1e-5f);
            float a = (v - m) * rs * eLag + eLab;
            float hOld = (float)s_h16[bb][lane];
            float y = a + hOld;
            float m2 = redsum64(y) * (1.0f / 64.0f);
            float var2 = redsum64(y * y) * (1.0f / 64.0f) - m2 * m2;
            float rs2 = rsqrtf(fmaxf(var2, 0.0f) + 1e-5f);
            float h0n = (y - m2) * rs2 * eLog + eLob;
            s_h16[bb][lane] = (_Float16)h0n;
            float p = h0n + eRb0;
#pragma unroll
            for (int d = 0; d < 12; d++)
                p = fmaf(s_x[sl][bb][d], s_rw0[d * 64 + lane], p);
            inp_w[(((size_t)(sIdx * Bn + gbase + bb)) * CT + tt) * 64 + lane] = (_Float16)p;
            if (tt + 1 < CT && lane < 12) {
                int d = lane;
                int t = t0 + tt + 1;
                float srcp = fmaxf((t + 0.5f) * sc - 0.5f, 0.f);
                int i0 = (int)floorf(srcp); if (i0 > Li - 1) i0 = Li - 1;
                int i1 = i0 + 1; if (i1 > Li - 1) i1 = Li - 1;
                float w = srcp - (float)i0;
                int gb = gbase + bb;
                s_x[sl ^ 1][bb][d] = x[(gb * Ln + st + i0) * 12 + d] * (1.0f - w) +
                                     x[(gb * Ln + st + i1) * 12 + d] * w;
            }
        }
        __syncthreads();
    }
    {
        int b = tid >> 6, jj = tid & 63;
        gstate[((size_t)(sIdx * Bn + gbase + b)) * 256 + jj] = (float)s_h16[b][jj];
    }
    gstate[((size_t)(sIdx * Bn + gbase + ks)) * 256 + 64 + j] = cS;
}

// ---------------------------------------------------------------------------
// Pass 2 body: layer 1 over a T-chunk. bid in [0,384). Reads G1R (f16,
// gate part stored PERMUTED so the read is lane-contiguous) with a one-
// timestep software prefetch (issued before the barriers, used next tt).
// ---------------------------------------------------------------------------
__device__ __forceinline__ void pass2_body(
    int bid,
    const float* __restrict__ gw1,
    const float* __restrict__ M1g, const float* __restrict__ bias1g,
    const float* __restrict__ w2g, const float* __restrict__ b2g,
    const float* __restrict__ lag, const float* __restrict__ lab,
    const float* __restrict__ log_, const float* __restrict__ lob,
    const _Float16* __restrict__ G1Rr, float* __restrict__ gstate,
    unsigned short* __restrict__ merged_w, int t0) {
    const int tid = threadIdx.x;
    const int sIdx = bid >> 7;
    const int gbase = (bid & 127) * BC;
    const int W = tid >> 6, lane = tid & 63;
    const int q = lane >> 2, ks = lane & 3;
    const int oct = lane >> 3, ks8 = lane & 7;
    const int j = W * 16 + q;
    const int cM = W * 32 + q * 2;
    const int uD = W * 16 + oct * 2;

    __shared__ __align__(16) _Float16 p2_h16[BC][72];
    __shared__ __align__(16) _Float16 p2_ht16[BC][72];
    __shared__ __align__(16) _Float16 p2_z16[BC][136];
    __shared__ float p2_t2[BC][64];

    __builtin_amdgcn_s_setprio(1);   // recurrent chain = critical path

    const float* gw1s = gw1 + (size_t)sIdx * 128 * 256;
    h2 wg16[4][8], wm16[2][8], ww16[2][8];
#pragma unroll
    for (int g = 0; g < 4; g++)
#pragma unroll
        for (int kk = 0; kk < 8; kk++)
            wg16[g][kk] = cvt2(gw1s[(64 + ks * 16 + 2 * kk) * 256 + j + 64 * g],
                               gw1s[(64 + ks * 16 + 2 * kk + 1) * 256 + j + 64 * g]);
    const float* M1s = M1g + (sIdx * 2 + 1) * 8192;
#pragma unroll
    for (int cc = 0; cc < 2; cc++)
#pragma unroll
        for (int kk = 0; kk < 8; kk++)
            wm16[cc][kk] = cvt2(M1s[(ks * 16 + 2 * kk) * 128 + cM + cc],
                                M1s[(ks * 16 + 2 * kk + 1) * 128 + cM + cc]);
    const float* w2s = w2g + (sIdx * 2 + 1) * 8192;
#pragma unroll
    for (int cc = 0; cc < 2; cc++)
#pragma unroll
        for (int kk = 0; kk < 8; kk++)
            ww16[cc][kk] = cvt2(w2s[(ks8 * 16 + 2 * kk) * 64 + uD + cc],
                                w2s[(ks8 * 16 + 2 * kk + 1) * 64 + uD + cc]);

    float h_b1[2] = {bias1g[(sIdx * 2 + 1) * 128 + cM], bias1g[(sIdx * 2 + 1) * 128 + cM + 1]};
    float h_b2[2] = {b2g[(sIdx * 2 + 1) * 64 + uD], b2g[(sIdx * 2 + 1) * 64 + uD + 1]};
    int ei = (sIdx * 2 + 1) * 64 + lane;
    float eLag = lag[ei], eLab = lab[ei], eLog = log_[ei], eLob = lob[ei];

    {
        int b = tid >> 6, jj = tid & 63;
        float hv = (t0 == 0) ? 0.f : gstate[((size_t)(sIdx * Bn + gbase + b)) * 256 + 128 + jj];
        p2_h16[b][jj] = (_Float16)hv;
    }
    float cS = (t0 == 0) ? 0.f
                         : gstate[((size_t)(sIdx * Bn + gbase + ks)) * 256 + 192 + j];
    __syncthreads();

    const size_t rowBase = ((size_t)(sIdx * Bn + gbase)) * CT;
    const int pOff = W * 64 + lane;   // permuted gate-part position (contiguous per wave)

    // prologue: seeds + residual for tt=0
    float g1rv[BC], rv;
#pragma unroll
    for (int b = 0; b < BC; b++)
        g1rv[b] = (float)G1Rr[(rowBase + (size_t)b * CT) * 320 + pOff];
    rv = (float)G1Rr[(rowBase + (size_t)W * CT) * 320 + 256 + lane];

    for (int tt = 0; tt < CT; tt++) {
        // ===== A =====
        float myF = 0, myI = 0, myG = 0, myO = 0;
#pragma unroll
        for (int b = 0; b < BC; b++) {
            const h8t* hp = (const h8t*)&p2_h16[b][ks * 16];
            h8t hv0 = hp[0], hv1 = hp[1];
            h2 hk[8];
            unpack8(hv0, hk); unpack8(hv1, hk + 4);
            float acc[4];
#pragma unroll
            for (int g = 0; g < 4; g++) acc[g] = (ks == g) ? g1rv[b] : 0.f;
#pragma unroll
            for (int kk = 0; kk < 8; kk++) {
#pragma unroll
                for (int g = 0; g < 4; g++)
                    acc[g] = fdot2f(wg16[g][kk], hk[kk], acc[g]);
            }
            float a0 = qsum(acc[0]);
            float a1 = qsum(acc[1]);
            float a2 = qsum(acc[2]);
            float a3 = qsum(acc[3]);
            if (ks == b) { myF = a0; myI = a1; myG = a2; myO = a3; }
        }
        {
            float cn = sigm(myF) * cS + sigm(myI) * tanhfast(myG);
            cS = cn;
            p2_ht16[ks][j] = (_Float16)(sigm(myO) * tanhfast(cn));
        }
        // prefetch next timestep's seeds + residual (consumed after 4 barriers)
        float g1rn[BC], rn;
        if (tt + 1 < CT) {
#pragma unroll
            for (int b = 0; b < BC; b++)
                g1rn[b] = (float)G1Rr[(rowBase + (size_t)b * CT + tt + 1) * 320 + pOff];
            rn = (float)G1Rr[(rowBase + (size_t)W * CT + tt + 1) * 320 + 256 + lane];
        } else {
#pragma unroll
            for (int b = 0; b < BC; b++) g1rn[b] = 0.f;
            rn = 0.f;
        }
        __syncthreads();
        // ===== C =====
        float z0 = 0, z1 = 0;
#pragma unroll
        for (int b = 0; b < BC; b++) {
            const h8t* hp = (const h8t*)&p2_ht16[b][ks * 16];
            h8t hv0 = hp[0], hv1 = hp[1];
            h2 hk[8];
            unpack8(hv0, hk); unpack8(hv1, hk + 4);
            float acc0 = (ks == 0) ? h_b1[0] : 0.f;
            float acc1 = (ks == 0) ? h_b1[1] : 0.f;
#pragma unroll
            for (int kk = 0; kk < 8; kk++) {
                acc0 = fdot2f(wm16[0][kk], hk[kk], acc0);
                acc1 = fdot2f(wm16[1][kk], hk[kk], acc1);
            }
            float a0 = qsum(acc0);
            float a1 = qsum(acc1);
            if (ks == b) { z0 = a0; z1 = a1; }
        }
        *(h2*)&p2_z16[ks][cM] = cvt2(gelu_ex(z0), gelu_ex(z1));
        __syncthreads();
        // ===== D =====
#pragma unroll
        for (int b = 0; b < BC; b++) {
            const h8t* zp = (const h8t*)&p2_z16[b][ks8 * 16];
            h8t zv0 = zp[0], zv1 = zp[1];
            h2 zk[8];
            unpack8(zv0, zk); unpack8(zv1, zk + 4);
            float acc0 = (ks8 == 0) ? h_b2[0] : 0.f;
            float acc1 = (ks8 == 0) ? h_b2[1] : 0.f;
#pragma unroll
            for (int kk = 0; kk < 8; kk++) {
                acc0 = fdot2f(ww16[0][kk], zk[kk], acc0);
                acc1 = fdot2f(ww16[1][kk], zk[kk], acc1);
            }
            float a0 = osum(acc0);
            float a1 = osum(acc1);
            if (ks8 == b) { p2_t2[b][uD] = a0; p2_t2[b][uD + 1] = a1; }
        }
        __syncthreads();
        // ===== E =====
        {
            const int bb = W;
            float v = p2_t2[bb][lane];
            float m = redsum64(v) * (1.0f / 64.0f);
            float var = redsum64(v * v) * (1.0f / 64.0f) - m * m;
            float rs = rsqrtf(fmaxf(var, 0.0f) + 1e-5f);
            float a = (v - m) * rs * eLag + eLab;
            float hOld = (float)p2_h16[bb][lane];
            float y = a + hOld;
            float m2 = redsum64(y) * (1.0f / 64.0f);
            float var2 = redsum64(y * y) * (1.0f / 64.0f) - m2 * m2;
            float rs2 = rsqrtf(fmaxf(var2, 0.0f) + 1e-5f);
            float h1n = (y - m2) * rs2 * eLog + eLob;
            p2_h16[bb][lane] = (_Float16)h1n;
            merged_w[(((size_t)(sIdx * Bn + gbase + bb)) * CT + tt) * 64 + lane] = f2u(h1n + rv);
        }
        __syncthreads();
#pragma unroll
        for (int b = 0; b < BC; b++) g1rv[b] = g1rn[b];
        rv = rn;
    }
    {
        int b = tid >> 6, jj = tid & 63;
        gstate[((size_t)(sIdx * Bn + gbase + b)) * 256 + 128 + jj] = (float)p2_h16[b][jj];
    }
    gstate[((size_t)(sIdx * Bn + gbase + ks)) * 256 + 192 + j] = cS;
}

// ---------------------------------------------------------------------------
// g1r body: bid in [0,258). Reads inp (f16) from prev launch, writes G1R (f16).
// f16 dot2 with pre-packed permuted weights; LDS tile stores input k-pairs.
// GTILES tiles per scale, 12 per block (86*12=1032 >= 1024).
// ---------------------------------------------------------------------------
__device__ __forceinline__ void g1r_body(
    int bid,
    const h2* __restrict__ gw1p16, const float* __restrict__ gb1p,
    const h2* __restrict__ rw1p16, const float* __restrict__ rb1,
    const _Float16* __restrict__ inp_r, _Float16* __restrict__ G1Rw) {
    const int tid = threadIdx.x;
    const int s = bid / 86;
    const int bb = bid % 86;
    __shared__ __align__(16) h2 s_in2[32][36];   // [k-pair][row]

    const int c4 = tid & 63, rg = tid >> 6;
    float4 bias = *(const float4*)(gb1p + s * 256 + c4 * 4);
    float rbias = rb1[s * 64 + c4];
    const h2* Wg = gw1p16 + (size_t)s * 32 * 256;
    const h2* Wr = rw1p16 + (size_t)s * 32 * 64;

    const size_t sRow = (size_t)s * Bn * CT;
    for (int tile = 0; tile < 12; tile++) {
        int tIdx = bb * 12 + tile;
        if (tIdx >= GTILES) break;
        int r0 = tIdx * 32;
        __syncthreads();
        for (int i = tid; i < 512; i += 256) {
            int r = i >> 4, kq = i & 15;
            h4 v = *(const h4*)(inp_r + (sRow + r0 + r) * 64 + kq * 4);
            s_in2[kq * 2 + 0][r] = mk2(v.x, v.y);
            s_in2[kq * 2 + 1][r] = mk2(v.z, v.w);
        }
        __syncthreads();
        float acc[8][4], accR[8];
#pragma unroll
        for (int r = 0; r < 8; r++) {
            acc[r][0] = bias.x; acc[r][1] = bias.y; acc[r][2] = bias.z; acc[r][3] = bias.w;
            accR[r] = rbias;
        }
#pragma unroll 4
        for (int k2 = 0; k2 < 32; k2++) {
            h8t wv = *(const h8t*)(Wg + (size_t)k2 * 256 + c4 * 4);
            h2 wp[4]; unpack8(wv, wp);
            h2 wR = Wr[k2 * 64 + c4];
            const h8t* ip = (const h8t*)&s_in2[k2][rg * 8];
            h8t iv0 = ip[0], iv1 = ip[1];
            h2 in2[8]; unpack8(iv0, in2); unpack8(iv1, in2 + 4);
#pragma unroll
            for (int r = 0; r < 8; r++) {
                acc[r][0] = fdot2f(in2[r], wp[0], acc[r][0]);
                acc[r][1] = fdot2f(in2[r], wp[1], acc[r][1]);
                acc[r][2] = fdot2f(in2[r], wp[2], acc[r][2]);
                acc[r][3] = fdot2f(in2[r], wp[3], acc[r][3]);
                accR[r] = fdot2f(in2[r], wR, accR[r]);
            }
        }
#pragma unroll
        for (int r = 0; r < 8; r++) {
            size_t row = sRow + r0 + rg * 8 + r;
            h4 o;
            o.x = (_Float16)acc[r][0]; o.y = (_Float16)acc[r][1];
            o.z = (_Float16)acc[r][2]; o.w = (_Float16)acc[r][3];
            *(h4*)(G1Rw + row * 320 + c4 * 4) = o;
            G1Rw[row * 320 + 256 + c4] = (_Float16)accR[r];
        }
    }
}

// ---------------------------------------------------------------------------
// combine body: bid in [0,512); each wave handles 16 (b,t) rows (B*CT=32768)
// ---------------------------------------------------------------------------
__device__ __forceinline__ void combine_body(
    int bid,
    const unsigned short* __restrict__ merged_r,
    const float* __restrict__ attn_w,
    void* __restrict__ outv, const int* __restrict__ flag, int t0) {
    int W = threadIdx.x >> 6, lane = threadIdx.x & 63;
    float aw = attn_w[lane];
    size_t stride = (size_t)Bn * CT * 64;
    int isf = *flag;
#pragma unroll
    for (int r = 0; r < 16; r++) {
        int wid = (bid * 4 + W) * 16 + r;
        int b = wid / CT, tt = wid % CT;
        size_t base = (((size_t)b) * CT + tt) * 64 + lane;
        float m0 = u2f(merged_r[base]);
        float m1 = u2f(merged_r[base + stride]);
        float m2 = u2f(merged_r[base + 2 * stride]);
        float e0 = redsum64(m0 * aw);
        float e1 = redsum64(m1 * aw);
        float e2 = redsum64(m2 * aw);
        float mx = fmaxf(e0, fmaxf(e1, e2));
        float x0 = expf(e0 - mx), x1 = expf(e1 - mx), x2 = expf(e2 - mx);
        float inv = 1.0f / (x0 + x1 + x2);
        float val = (x0 * m0 + x1 * m1 + x2 * m2) * inv;
        size_t ob = (((size_t)b) * Ln + t0 + tt) * 64 + lane;
        if (isf) ((float*)outv)[ob] = val;
        else ((unsigned short*)outv)[ob] = f2u(val);
    }
}

// ---------------------------------------------------------------------------
// Mega kernel: software-pipelined stages, all deps come from the PREVIOUS
// launch.  Launch m: pass1(m) | g1r(m-1) | pass2(m-2) | combine(m-3).
// Ping-pong buffers by chunk parity.  CT=64 halves launch count (11 vs 19):
// weight-prologue + launch overhead amortized over 2x timesteps.
// ---------------------------------------------------------------------------
__global__ __launch_bounds__(256) __attribute__((amdgpu_waves_per_eu(2, 5)))
void mega_kernel(
    const float* __restrict__ x, const float* __restrict__ gw0,
    const float* __restrict__ gb0, const float* __restrict__ gw1,
    const h2* __restrict__ gw1p16, const float* __restrict__ gb1p,
    const h2* __restrict__ rw1p16,
    const float* __restrict__ M1g, const float* __restrict__ bias1g,
    const float* __restrict__ w2g, const float* __restrict__ b2g,
    const float* __restrict__ lag, const float* __restrict__ lab,
    const float* __restrict__ log_, const float* __restrict__ lob,
    const float* __restrict__ rw0, const float* __restrict__ rb0,
    const float* __restrict__ rb1,
    float* __restrict__ gstate,
    _Float16* __restrict__ inpB, _Float16* __restrict__ G1RB,
    unsigned short* __restrict__ mergedB,
    const float* __restrict__ attn_w, void* __restrict__ outv,
    const int* __restrict__ flag,
    int c_p1, int c_g1r, int c_p2, int c_comb) {
    int bid = blockIdx.x;
    if (bid < P1OFF) {
        if (c_p2 >= 0) {
            const _Float16* g1r_r = G1RB + (size_t)(c_p2 & 1) * NG1R;
            unsigned short* merged_w = mergedB + (size_t)(c_p2 & 1) * NMERG;
            pass2_body(bid, gw1, M1g, bias1g, w2g, b2g, lag, lab, log_, lob,
                       g1r_r, gstate, merged_w, c_p2 * CT);
        }
    } else if (bid < GROFF) {
        if (c_p1 >= 0) {
            _Float16* inp_w = inpB + (size_t)(c_p1 & 1) * NINP;
            pass1_body(bid - P1OFF, x, gw0, gb0, M1g, bias1g, w2g, b2g,
                       lag, lab, log_, lob, rw0, rb0, gstate, inp_w, c_p1 * CT);
        }
    } else if (bid < CBOFF) {
        if (c_g1r >= 0) {
            const _Float16* inp_r = inpB + (size_t)(c_g1r & 1) * NINP;
            _Float16* g1r_w = G1RB + (size_t)(c_g1r & 1) * NG1R;
            g1r_body(bid - GROFF, gw1p16, gb1p, rw1p16, rb1, inp_r, g1r_w);
        }
    } else {
        if (c_comb >= 0) {
            const unsigned short* merged_r = mergedB + (size_t)(c_comb & 1) * NMERG;
            combine_body(bid - CBOFF, merged_r, attn_w, outv, flag, c_comb * CT);
        }
    }
}

extern "C" void kernel_launch(void* const* d_in, const int* in_sizes, int n_in,
                              void* d_out, int out_size, void* d_ws, size_t ws_size,
                              hipStream_t stream) {
    (void)out_size; (void)ws_size;
    int* flag = (int*)d_ws;
    float* canon = (float*)((char*)d_ws + 16);

    ConvArgs ca;
    size_t tot = 0;
    unsigned nblocks = 0;
    for (int i = 0; i < NIN; i++) {
        ca.src[i] = d_in[i];
        ca.dstOff[i] = (unsigned)tot;
        unsigned n = (unsigned)in_sizes[i];
        ca.n[i] = n;
        ca.blockStart[i] = nblocks;
        nblocks += (n + 2047) / 2048;
        tot += n;
    }
    ca.blockStart[NIN] = nblocks;

    size_t canonBytes = (tot * 4 + 15) & ~(size_t)15;
    char* p = (char*)d_ws + 16 + canonBytes;
    float* M1 = (float*)p;       p += (size_t)3 * 2 * 64 * 128 * 4;
    float* bias1 = (float*)p;    p += (size_t)3 * 2 * 128 * 4;
    float* gb1p = (float*)p;     p += (size_t)3 * 256 * 4;
    h2* gw1p16 = (h2*)p;         p += (size_t)3 * 32 * 256 * 4;   // h2 = 4B
    h2* rw1p16 = (h2*)p;         p += (size_t)3 * 32 * 64 * 4;
    float* gstate = (float*)p;   p += (size_t)3 * 512 * 256 * 4;
    p = (char*)(((uintptr_t)p + 15) & ~(uintptr_t)15);
    _Float16* inpB = (_Float16*)p;      p += 2 * NINP * 2;
    _Float16* G1RB = (_Float16*)p;      p += 2 * NG1R * 2;
    p = (char*)(((uintptr_t)p + 15) & ~(uintptr_t)15);
    unsigned short* mergedB = (unsigned short*)p;   // 2 * NMERG * 2 bytes

    const float* x    = canon + ca.dstOff[0];
    const float* gw0  = canon + ca.dstOff[1];
    const float* gb0  = canon + ca.dstOff[2];
    const float* gw1  = canon + ca.dstOff[3];
    const float* gb1  = canon + ca.dstOff[4];
    const float* mi_w = canon + ca.dstOff[5];
    const float* mi_b = canon + ca.dstOff[6];
    const float* mo_w = canon + ca.dstOff[7];
    const float* mo_b = canon + ca.dstOff[8];
    const float* w1   = canon + ca.dstOff[9];
    const float* b1   = canon + ca.dstOff[10];
    const float* w2   = canon + ca.dstOff[11];
    const float* b2   = canon + ca.dstOff[12];
    const float* lag  = canon + ca.dstOff[13];
    const float* lab  = canon + ca.dstOff[14];
    const float* log_ = canon + ca.dstOff[15];
    const float* lob  = canon + ca.dstOff[16];
    const float* rw0  = canon + ca.dstOff[17];
    const float* rb0  = canon + ca.dstOff[18];
    const float* rw1  = canon + ca.dstOff[19];
    const float* rb1  = canon + ca.dstOff[20];
    const float* attn_w = canon + ca.dstOff[21];

    convert_kernel<<<dim3(nblocks), dim3(256), 0, stream>>>(ca, canon);
    setup_kernel<<<dim3(10), dim3(256), 0, stream>>>(
        (const unsigned short*)d_in[0], flag,
        mi_w, mi_b, mo_w, mo_b, w1, b1, M1, bias1,
        gw1, gb1, rw1, gw1p16, gb1p, rw1p16);

    // software pipeline: launch m runs pass1(m), g1r(m-1), pass2(m-2), combine(m-3)
    for (int m = 0; m <= NCHUNK + 2; m++) {
        int c1 = (m < NCHUNK) ? m : -1;
        int cg = (m - 1 >= 0 && m - 1 < NCHUNK) ? m - 1 : -1;
        int c2 = (m - 2 >= 0 && m - 2 < NCHUNK) ? m - 2 : -1;
        int cc = (m - 3 >= 0 && m - 3 < NCHUNK) ? m - 3 : -1;
        mega_kernel<<<dim3(MEGABLK), dim3(256), 0, stream>>>(
            x, gw0, gb0, gw1, gw1p16, gb1p, rw1p16, M1, bias1, w2, b2,
            lag, lab, log_, lob, rw0, rb0, rb1, gstate, inpB, G1RB, mergedB,
            attn_w, d_out, flag, c1, cg, c2, cc);
    }
}